// Round 11
// baseline (398.562 us; speedup 1.0000x reference)
//
#include <hip/hip_runtime.h>
#include <hip/hip_bf16.h>
#include <cstdint>

// ---------------------------------------------------------------------------
#define IMGSZ 224
#define OUTSZ 112
#define POOLSZ 56
#define OCN 128
#define BN_ 32
#define PIX1 (OUTSZ*OUTSZ)     // 12544
#define PIX2 (POOLSZ*POOLSZ)   // 3136
#define HP 58                  // padded pooled dim (56 + 2)
#define HSTRIDE (HP*HP*OCN)    // elems per n in h2p
#define PW 240                 // padded input row stride (x in [-3,236))
#define PH 233                 // padded input rows (y in [-3,230))
#define PPL (PH*PW)            // 55920 elems per padded plane
#define K1C 192                // conv1 K: 24 groups of 8 = (ic*7+ky)*8+kx layout

typedef float f32x4 __attribute__((ext_vector_type(4)));
typedef short bf16x8 __attribute__((ext_vector_type(8)));
struct alignas(4) u4a { unsigned x, y, z, w; };   // 4B-aligned 16B load

__device__ inline short f2bf(float v) {
    __hip_bfloat16 h = __float2bfloat16(v);
    return *(short*)&h;
}
__device__ inline unsigned pack2bf(float a, float b) {
    return (unsigned short)f2bf(a) | ((unsigned)(unsigned short)f2bf(b) << 16);
}
__device__ inline bf16x8 ldb8(const short* p) {   // 16B load, 4B-aligned
    u4a t = *(const u4a*)p;
    union { u4a u; bf16x8 v; } c; c.u = t; return c.v;
}

// ---------------------------------------------------------------------------
// Fused setup: [0,49) map ; [49,145) wpack1 ; [145,721) wconv ;
// [721,785) stats zero ; [785,2609) h2p halo zero.
__global__ __launch_bounds__(256) void k_setup(const float* __restrict__ w1,
                                               short* __restrict__ w1b,
                                               const float* __restrict__ w2,
                                               short* __restrict__ w2b,
                                               int2* __restrict__ map,
                                               float* __restrict__ stats,
                                               unsigned* __restrict__ h2p) {
    int blk = blockIdx.x;
    int tid = threadIdx.x;
    if (blk < 49) {
        int p = blk * 256 + tid;
        int oy = p / OUTSZ, ox = p % OUTSZ;
        int e = min(min(oy, ox), min(111 - oy, 111 - ox));
        int s = e >> 3;
        int a = 16 * s, b = a + 16, c = 224 - b, d = 224 - a;
        int ao = a >> 1, bo = b >> 1, co = c >> 1, dd = d >> 1;
        int ti, li, bi, ri;
        if      (oy >= ao && oy < bo && ox >= ao && ox < co) { ti=a; li=a; bi=b; ri=c; }
        else if (oy >= bo && oy < dd && ox >= ao && ox < bo) { ti=b; li=a; bi=d; ri=b; }
        else if (oy >= co && oy < dd && ox >= bo && ox < dd) { ti=c; li=b; bi=d; ri=d; }
        else                                                 { ti=a; li=c; bi=c; ri=d; }
        float scale = (float)(2.0 - (double)s * 0.16666666666666666);
        int tip = (int)((float)(ti + 6) / scale) - 3;
        int lip = (int)((float)(li + 6) / scale) - 3;
        int bip = (int)((float)(bi + 6) / scale) + 3;
        int rip = (int)((float)(ri + 6) / scale) + 3;
        int fh = (bip - tip - 7) / 2 + 1;
        int fw = (rip - lip - 7) / 2 + 1;
        int to = ti >> 1, lo = li >> 1, bo2 = bi >> 1, ro = ri >> 1;
        int i = oy - to, j = ox - lo;
        int pp = (i * fh) / (bo2 - to);
        int qq = (j * fw) / (ro - lo);
        map[p] = make_int2(tip + 2 * pp, lip + 2 * qq);
    } else if (blk < 145) {
        int idx = (blk - 49) * 256 + tid;
        int oc = idx / K1C, k = idx % K1C;
        int g8 = k >> 3, e2 = k & 7;
        float v = 0.f;
        if (g8 < 21 && e2 < 7) {
            int ic = g8 / 7, ky = g8 - ic * 7;
            v = w1[((oc * 3 + ic) * 7 + ky) * 7 + e2];
        }
        w1b[idx] = f2bf(v);
    } else if (blk < 721) {
        int idx = (blk - 145) * 256 + tid;
        int s = idx % 9;
        int t = idx / 9;
        int ic = t & 127;
        int oc = t >> 7;
        w2b[(s * OCN + oc) * OCN + ic] = f2bf(w2[idx]);
    } else if (blk < 785) {
        stats[(blk - 721) * 256 + tid] = 0.f;
    } else {
        int idx = blk - 785;                  // 0..1823
        int bx = idx % 57, n = idx / 57;
        int c2 = tid & 63, po = tid >> 6;
        int pp = bx * 4 + po;                 // 0..227
        int y, x;
        if      (pp < 58)  { y = 0;  x = pp; }
        else if (pp < 116) { y = 57; x = pp - 58; }
        else if (pp < 172) { y = pp - 116 + 1; x = 0; }
        else               { y = pp - 172 + 1; x = 57; }
        h2p[(size_t)n * (HSTRIDE / 2) + (y * HP + x) * 64 + c2] = 0u;
    }
}

// ---------------------------------------------------------------------------
// Zero-haloed padded bf16 input, TWO copies: padA[x] = img[x-3], padB[x] = img[x-2]
__global__ __launch_bounds__(256) void k_pad(const float* __restrict__ inp,
                                             short* __restrict__ padA,
                                             short* __restrict__ padB) {
    int x = threadIdx.x;
    if (x >= PW) return;
    int y = blockIdx.x;       // 0..232
    int pl = blockIdx.y;      // 0..95
    int iy = y - 3;
    bool yok = (unsigned)iy < 224u;
    const float* src = inp + (size_t)pl * 50176 + iy * 224;
    float vA = (yok && (unsigned)(x - 3) < 224u) ? src[x - 3] : 0.f;
    float vB = (yok && (unsigned)(x - 2) < 224u) ? src[x - 2] : 0.f;
    size_t o = (size_t)pl * PPL + y * PW + x;
    padA[o] = f2bf(vA);
    padB[o] = f2bf(vB);
}

// ---------------------------------------------------------------------------
// conv1 via MFMA. Wave = 64 oc x 32 px; block = 4 waves x 32 px = 128 px,
// ALL on the same 64-oc A-slice (24 KB, L1-resident). oc-half = blockIdx.x&1.
__global__ __launch_bounds__(256, 4) void k_conv1m(const short* __restrict__ padA,
                                                   const short* __restrict__ padB,
                                                   const short* __restrict__ w1b,
                                                   const int2* __restrict__ map,
                                                   short* __restrict__ out1b,
                                                   float* __restrict__ sum1x,
                                                   float* __restrict__ sq1x) {
    __shared__ float sred[4][64][2];   // 2 KB
    int tid = threadIdx.x;
    int wave = tid >> 6, lane = tid & 63;
    int q = lane >> 4, l16 = lane & 15;
    int ochalf = blockIdx.x & 1;
    int pxblk = blockIdx.x >> 1;                      // 0..97
    int n = blockIdx.y;
    int px0 = pxblk * 128 + wave * 32 + l16;
    int px1 = px0 + 16;
    int2 m0 = map[px0];
    int2 m1 = map[px1];
    size_t bn = (size_t)n * 3 * PPL;
    const short* r0 = ((m0.y & 1) ? padB + (m0.y - 1) : padA + m0.y) + bn + m0.x * PW;
    const short* r1 = ((m1.y & 1) ? padB + (m1.y - 1) : padA + m1.y) + bn + m1.x * PW;

    bf16x8 ld[12];
#pragma unroll
    for (int icc = 0; icc < 6; icc++) {
        int g8 = (icc == 5) ? 20 : (icc * 4 + q);
        int ic = (g8 >= 7) + (g8 >= 14);
        int ky = g8 - ic * 7;
        int off = ic * PPL + ky * PW;
        ld[icc * 2]     = ldb8(r0 + off);
        ld[icc * 2 + 1] = ldb8(r1 + off);
    }

    f32x4 acc[4][2];
#pragma unroll
    for (int t = 0; t < 4; t++) { acc[t][0] = (f32x4){0,0,0,0}; acc[t][1] = (f32x4){0,0,0,0}; }

    const short* wb = w1b + (ochalf * 64 + l16) * K1C + q * 8;
#pragma unroll
    for (int icc = 0; icc < 6; icc++) {
        bf16x8 bf0 = ld[icc * 2];
        bf16x8 bf1 = ld[icc * 2 + 1];
        const short* wk = wb + icc * 32;
#pragma unroll
        for (int t = 0; t < 4; t++) {
            bf16x8 af = *(const bf16x8*)(wk + t * 16 * K1C);
            acc[t][0] = __builtin_amdgcn_mfma_f32_16x16x32_bf16(af, bf0, acc[t][0], 0, 0, 0);
            acc[t][1] = __builtin_amdgcn_mfma_f32_16x16x32_bf16(af, bf1, acc[t][1], 0, 0, 0);
        }
    }

    // epilogue: C layout col(px)=l16, row(oc_local)=q*4+r ; store NHWC bf16
    short* ob = out1b + ((size_t)(n * PIX1) + px0) * OCN + ochalf * 64 + q * 4;
#pragma unroll
    for (int t = 0; t < 4; t++) {
#pragma unroll
        for (int g = 0; g < 2; g++) {
            f32x4 a = acc[t][g];
            uint2 u;
            u.x = pack2bf(a[0], a[1]);
            u.y = pack2bf(a[2], a[3]);
            *(uint2*)(ob + (size_t)g * 16 * OCN + t * 16) = u;
        }
    }

    // fused BN1 stats: shuffle-reduce 16 px-lanes -> LDS -> block pass
#pragma unroll
    for (int t = 0; t < 4; t++) {
#pragma unroll
        for (int r = 0; r < 4; r++) {
            float a0 = acc[t][0][r], a1 = acc[t][1][r];
            float s = a0 + a1;
            float z = fmaf(a0, a0, a1 * a1);
#pragma unroll
            for (int msk = 1; msk < 16; msk <<= 1) {
                s += __shfl_xor(s, msk, 64);
                z += __shfl_xor(z, msk, 64);
            }
            if (l16 == 0) {
                int ocl = t * 16 + q * 4 + r;     // 0..63
                sred[wave][ocl][0] = s;
                sred[wave][ocl][1] = z;
            }
        }
    }
    __syncthreads();
    if (tid < 64) {
        float s = sred[0][tid][0] + sred[1][tid][0] + sred[2][tid][0] + sred[3][tid][0];
        float z = sred[0][tid][1] + sred[1][tid][1] + sred[2][tid][1] + sred[3][tid][1];
        int oc = ochalf * 64 + tid;
        atomicAdd(&sum1x[n * OCN + oc], s);
        atomicAdd(&sq1x[n * OCN + oc], z);
    }
}

// ---------------------------------------------------------------------------
// Finalize BN params from per-n partial sums: 32x128 -> scale/shift.
__global__ void k_fin2(const float* __restrict__ sumx, const float* __restrict__ sqx,
                       const float* __restrict__ gamma, const float* __restrict__ beta,
                       float invN, float* __restrict__ scale, float* __restrict__ shift) {
    int c = threadIdx.x;
    if (c >= OCN) return;
    float s = 0.f, q = 0.f;
    for (int n = 0; n < BN_; n++) { s += sumx[n * OCN + c]; q += sqx[n * OCN + c]; }
    float m = s * invN;
    float v = q * invN - m * m;
    float sc = gamma[c] * rsqrtf(v + 1e-5f);
    scale[c] = sc;
    shift[c] = beta[c] - m * sc;
}

// ---------------------------------------------------------------------------
// BN1 affine + 3x3/2 maxpool + ReLU: NHWC bf16 (112x112) -> padded NHWC bf16 (58x58)
__global__ __launch_bounds__(256) void k_bnpool(const unsigned* __restrict__ out1b,
                                                const float* __restrict__ scale,
                                                const float* __restrict__ shift,
                                                unsigned* __restrict__ h2p) {
    int tid = threadIdx.x;
    int c2 = tid & 63, po = tid >> 6;
    int pp = blockIdx.x * 4 + po;
    int n = blockIdx.y;
    int py = pp / POOLSZ, px = pp % POOLSZ;
    const unsigned* base = out1b + (size_t)n * PIX1 * 64;
    float sc0 = scale[2 * c2],     sh0 = shift[2 * c2];
    float sc1 = scale[2 * c2 + 1], sh1 = shift[2 * c2 + 1];
    float m0 = -1e30f, m1 = -1e30f;
#pragma unroll
    for (int dy = 0; dy < 3; dy++) {
        int y = 2 * py - 1 + dy;
        if ((unsigned)y >= (unsigned)OUTSZ) continue;
#pragma unroll
        for (int dx = 0; dx < 3; dx++) {
            int x = 2 * px - 1 + dx;
            if ((unsigned)x >= (unsigned)OUTSZ) continue;
            unsigned u = base[(size_t)(y * OUTSZ + x) * 64 + c2];
            float v0 = __uint_as_float(u << 16);
            float v1 = __uint_as_float(u & 0xffff0000u);
            m0 = fmaxf(m0, fmaf(sc0, v0, sh0));
            m1 = fmaxf(m1, fmaf(sc1, v1, sh1));
        }
    }
    m0 = fmaxf(m0, 0.f); m1 = fmaxf(m1, 0.f);
    h2p[(size_t)n * (HSTRIDE / 2) + ((py + 1) * HP + (px + 1)) * 64 + c2] = pack2bf(m0, m1);
}

// ---------------------------------------------------------------------------
// conv2 via bf16 MFMA. Wave = 64 oc x 64 px; block = 4 same-oc-half waves
// = 64 oc x 256 px. s OUTER: per-s A-slice = 64oc x 128K = 16 KB, L1-resident,
// shared by all 4 waves. Grid 26 x 32 = 832 blocks (2x waves vs R10) for
// latency hiding. Fused BN2 stats.
__global__ __launch_bounds__(256, 3) void k_conv2m(const short* __restrict__ h2p,
                                                   const short* __restrict__ w2b,
                                                   short* __restrict__ out2b,
                                                   float* __restrict__ sum2x,
                                                   float* __restrict__ sq2x) {
    __shared__ float sred[4][64][2];
    int tid = threadIdx.x;
    int wave = tid >> 6, lane = tid & 63;
    int q = lane >> 4, l16 = lane & 15;
    int ochalf = blockIdx.x & 1;
    int pxblk = blockIdx.x >> 1;                      // 0..12
    int n = blockIdx.y;
    int pxb = pxblk * 256 + wave * 64 + l16;
    bool st[4];
    int bofs[4];
#pragma unroll
    for (int g = 0; g < 4; g++) {
        int p = pxb + g * 16;
        st[g] = p < PIX2;
        int pc = st[g] ? p : (PIX2 - 1);
        int y = pc / POOLSZ, x = pc % POOLSZ;
        bofs[g] = (y * HP + x) * OCN;
    }
    const short* hb = h2p + (size_t)n * HSTRIDE;

    f32x4 acc[4][4];
#pragma unroll
    for (int t = 0; t < 4; t++)
#pragma unroll
        for (int g = 0; g < 4; g++) acc[t][g] = (f32x4){0, 0, 0, 0};

    for (int s = 0; s < 9; s++) {                      // runtime outer
        int rowoff = ((s / 3) * HP + (s % 3)) * OCN;
        const short* wsl = w2b + (s * OCN + ochalf * 64 + l16) * OCN;
#pragma unroll
        for (int icc = 0; icc < 4; icc++) {
            int kof = icc * 32 + q * 8;
            bf16x8 bf[4];
#pragma unroll
            for (int g = 0; g < 4; g++) bf[g] = *(const bf16x8*)(hb + bofs[g] + rowoff + kof);
            const short* wbase = wsl + kof;
#pragma unroll
            for (int t = 0; t < 4; t++) {
                bf16x8 af = *(const bf16x8*)(wbase + t * 16 * OCN);
#pragma unroll
                for (int g = 0; g < 4; g++)
                    acc[t][g] = __builtin_amdgcn_mfma_f32_16x16x32_bf16(af, bf[g], acc[t][g], 0, 0, 0);
            }
        }
    }
    // C/D layout: col(px)=l16, row(oc_local)=q*4+reg ; store NCHW bf16
    short* on = out2b + (size_t)n * OCN * PIX2;
#pragma unroll
    for (int t = 0; t < 4; t++) {
        int ocb = ochalf * 64 + t * 16 + q * 4;
#pragma unroll
        for (int g = 0; g < 4; g++) {
            if (!st[g]) continue;
            int p = pxb + g * 16;
#pragma unroll
            for (int r = 0; r < 4; r++)
                on[(size_t)(ocb + r) * PIX2 + p] = f2bf(acc[t][g][r]);
        }
    }
    // fused BN2 stats (every wave writes sred; masked groups contribute 0)
#pragma unroll
    for (int t = 0; t < 4; t++) {
#pragma unroll
        for (int r = 0; r < 4; r++) {
            float s = 0.f, z = 0.f;
#pragma unroll
            for (int g = 0; g < 4; g++) {
                if (!st[g]) continue;
                float v = acc[t][g][r];
                s += v;
                z = fmaf(v, v, z);
            }
#pragma unroll
            for (int msk = 1; msk < 16; msk <<= 1) {
                s += __shfl_xor(s, msk, 64);
                z += __shfl_xor(z, msk, 64);
            }
            if (l16 == 0) {
                int ocl = t * 16 + q * 4 + r;
                sred[wave][ocl][0] = s;
                sred[wave][ocl][1] = z;
            }
        }
    }
    __syncthreads();
    if (tid < 64) {
        float s = sred[0][tid][0] + sred[1][tid][0] + sred[2][tid][0] + sred[3][tid][0];
        float z = sred[0][tid][1] + sred[1][tid][1] + sred[2][tid][1] + sred[3][tid][1];
        int oc = ochalf * 64 + tid;
        atomicAdd(&sum2x[n * OCN + oc], s);
        atomicAdd(&sq2x[n * OCN + oc], z);
    }
}

// BN2 affine + ReLU: NCHW bf16 temp -> fp32 d_out. 2 px per thread.
__global__ __launch_bounds__(256) void k_bnrelu(const unsigned* __restrict__ in2,
                                                float* __restrict__ y,
                                                const float* __restrict__ scale,
                                                const float* __restrict__ shift) {
    size_t i2 = (size_t)blockIdx.x * 256 + threadIdx.x;   // 25088*256 = 6,422,528 exact
    int c = (int)((i2 / (PIX2 / 2)) & (OCN - 1));
    unsigned u = in2[i2];
    float v0 = __uint_as_float(u << 16);
    float v1 = __uint_as_float(u & 0xffff0000u);
    float sc = scale[c], sh = shift[c];
    float2 o;
    o.x = fmaxf(fmaf(sc, v0, sh), 0.f);
    o.y = fmaxf(fmaf(sc, v1, sh), 0.f);
    *(float2*)(y + 2 * i2) = o;
}

// ---------------------------------------------------------------------------
extern "C" void kernel_launch(void* const* d_in, const int* in_sizes, int n_in,
                              void* d_out, int out_size, void* d_ws, size_t ws_size,
                              hipStream_t stream) {
    const float* inp = (const float*)d_in[0];
    const float* w1  = (const float*)d_in[1];
    const float* g1  = (const float*)d_in[2];
    const float* b1  = (const float*)d_in[3];
    const float* w2  = (const float*)d_in[4];
    const float* g2  = (const float*)d_in[5];
    const float* b2  = (const float*)d_in[6];
    float* out = (float*)d_out;

    char* ws = (char*)d_ws;
    int2*  map   = (int2*)ws;                         // 100,352 B
    float* stats = (float*)(ws + 102400);             // 65,536 B zeroed in k_setup
    short* w2b   = (short*)(ws + 176128);             // 294,912 B -> 471,040
    short* w1b   = (short*)(ws + 471040);             // 49,152 B  -> 520,192
    short* padA  = (short*)(ws + 520192);             // 10,736,640 B -> 11,256,832
    short* padB  = (short*)(ws + 11256832ULL);        // 10,736,640 B -> 21,993,472
    short* h2p   = (short*)(ws + 21993472ULL);        // 27,557,888 B -> 49,551,360
    short* out1b = (short*)(ws + 49551360ULL);        // 102,760,448 B -> 152,311,808
    short* out2b = (short*)(ws + 152311808ULL);       // 25,690,112 B -> 178,001,920

    float* sum1x = stats;                // 32*128
    float* sq1x  = stats + 4096;
    float* sum2x = stats + 8192;
    float* sq2x  = stats + 12288;
    float* SC1 = stats + 16384 - 384;   // inside zeroed 16384-float range? no:
    // BN param slots live right after the 16384 zeroed floats; k_fin2 writes
    // them before any reader, so zero-init is not required.
    SC1 = stats + 16384;
    float* SH1 = stats + 16512;
    float* SC2 = stats + 16640, *SH2 = stats + 16768;

    k_setup <<<dim3(2609), 256, 0, stream>>>(w1, w1b, w2, w2b, map, stats, (unsigned*)h2p);
    k_pad   <<<dim3(PH, 96), 256, 0, stream>>>(inp, padA, padB);
    k_conv1m<<<dim3(196, BN_), 256, 0, stream>>>(padA, padB, w1b, map, out1b, sum1x, sq1x);
    k_fin2  <<<1, 128, 0, stream>>>(sum1x, sq1x, g1, b1, 1.f / (BN_ * PIX1), SC1, SH1);
    k_bnpool<<<dim3(PIX2 / 4, BN_), 256, 0, stream>>>((const unsigned*)out1b, SC1, SH1, (unsigned*)h2p);
    k_conv2m<<<dim3(26, BN_), 256, 0, stream>>>(h2p, w2b, out2b, sum2x, sq2x);
    k_fin2  <<<1, 128, 0, stream>>>(sum2x, sq2x, g2, b2, 1.f / (BN_ * PIX2), SC2, SH2);
    k_bnrelu<<<dim3(25088), 256, 0, stream>>>((const unsigned*)out2b, out, SC2, SH2);
}

// Round 12
// 367.849 us; speedup vs baseline: 1.0835x; 1.0835x over previous
//
#include <hip/hip_runtime.h>
#include <hip/hip_bf16.h>
#include <cstdint>

// ---------------------------------------------------------------------------
#define IMGSZ 224
#define OUTSZ 112
#define POOLSZ 56
#define OCN 128
#define BN_ 32
#define PIX1 (OUTSZ*OUTSZ)     // 12544
#define PIX2 (POOLSZ*POOLSZ)   // 3136
#define HP 58                  // padded pooled dim (56 + 2)
#define HSTRIDE (HP*HP*OCN)    // elems per n in h2p
#define PW 240                 // padded input row stride (x in [-3,236))
#define PH 233                 // padded input rows (y in [-3,230))
#define PPL (PH*PW)            // 55920 elems per padded plane
#define K1C 192                // conv1 K: 24 groups of 8 = (ic*7+ky)*8+kx layout

typedef float f32x4 __attribute__((ext_vector_type(4)));
typedef short bf16x8 __attribute__((ext_vector_type(8)));
struct alignas(4) u4a { unsigned x, y, z, w; };   // 4B-aligned 16B load

__device__ inline short f2bf(float v) {
    __hip_bfloat16 h = __float2bfloat16(v);
    return *(short*)&h;
}
__device__ inline unsigned pack2bf(float a, float b) {
    return (unsigned short)f2bf(a) | ((unsigned)(unsigned short)f2bf(b) << 16);
}
__device__ inline bf16x8 ldb8(const short* p) {   // 16B load, 4B-aligned
    u4a t = *(const u4a*)p;
    union { u4a u; bf16x8 v; } c; c.u = t; return c.v;
}

// ---------------------------------------------------------------------------
// Fused setup: [0,49) map ; [49,145) wpack1 ; [145,721) wconv ;
// [721,785) stats zero ; [785,2609) h2p halo zero.
__global__ __launch_bounds__(256) void k_setup(const float* __restrict__ w1,
                                               short* __restrict__ w1b,
                                               const float* __restrict__ w2,
                                               short* __restrict__ w2b,
                                               int2* __restrict__ map,
                                               float* __restrict__ stats,
                                               unsigned* __restrict__ h2p) {
    int blk = blockIdx.x;
    int tid = threadIdx.x;
    if (blk < 49) {
        int p = blk * 256 + tid;
        int oy = p / OUTSZ, ox = p % OUTSZ;
        int e = min(min(oy, ox), min(111 - oy, 111 - ox));
        int s = e >> 3;
        int a = 16 * s, b = a + 16, c = 224 - b, d = 224 - a;
        int ao = a >> 1, bo = b >> 1, co = c >> 1, dd = d >> 1;
        int ti, li, bi, ri;
        if      (oy >= ao && oy < bo && ox >= ao && ox < co) { ti=a; li=a; bi=b; ri=c; }
        else if (oy >= bo && oy < dd && ox >= ao && ox < bo) { ti=b; li=a; bi=d; ri=b; }
        else if (oy >= co && oy < dd && ox >= bo && ox < dd) { ti=c; li=b; bi=d; ri=d; }
        else                                                 { ti=a; li=c; bi=c; ri=d; }
        float scale = (float)(2.0 - (double)s * 0.16666666666666666);
        int tip = (int)((float)(ti + 6) / scale) - 3;
        int lip = (int)((float)(li + 6) / scale) - 3;
        int bip = (int)((float)(bi + 6) / scale) + 3;
        int rip = (int)((float)(ri + 6) / scale) + 3;
        int fh = (bip - tip - 7) / 2 + 1;
        int fw = (rip - lip - 7) / 2 + 1;
        int to = ti >> 1, lo = li >> 1, bo2 = bi >> 1, ro = ri >> 1;
        int i = oy - to, j = ox - lo;
        int pp = (i * fh) / (bo2 - to);
        int qq = (j * fw) / (ro - lo);
        map[p] = make_int2(tip + 2 * pp, lip + 2 * qq);
    } else if (blk < 145) {
        int idx = (blk - 49) * 256 + tid;
        int oc = idx / K1C, k = idx % K1C;
        int g8 = k >> 3, e2 = k & 7;
        float v = 0.f;
        if (g8 < 21 && e2 < 7) {
            int ic = g8 / 7, ky = g8 - ic * 7;
            v = w1[((oc * 3 + ic) * 7 + ky) * 7 + e2];
        }
        w1b[idx] = f2bf(v);
    } else if (blk < 721) {
        int idx = (blk - 145) * 256 + tid;
        int s = idx % 9;
        int t = idx / 9;
        int ic = t & 127;
        int oc = t >> 7;
        w2b[(s * OCN + oc) * OCN + ic] = f2bf(w2[idx]);
    } else if (blk < 785) {
        stats[(blk - 721) * 256 + tid] = 0.f;
    } else {
        int idx = blk - 785;                  // 0..1823
        int bx = idx % 57, n = idx / 57;
        int c2 = tid & 63, po = tid >> 6;
        int pp = bx * 4 + po;                 // 0..227
        int y, x;
        if      (pp < 58)  { y = 0;  x = pp; }
        else if (pp < 116) { y = 57; x = pp - 58; }
        else if (pp < 172) { y = pp - 116 + 1; x = 0; }
        else               { y = pp - 172 + 1; x = 57; }
        h2p[(size_t)n * (HSTRIDE / 2) + (y * HP + x) * 64 + c2] = 0u;
    }
}

// ---------------------------------------------------------------------------
// Zero-haloed padded bf16 input, TWO copies: padA[x] = img[x-3], padB[x] = img[x-2]
__global__ __launch_bounds__(256) void k_pad(const float* __restrict__ inp,
                                             short* __restrict__ padA,
                                             short* __restrict__ padB) {
    int x = threadIdx.x;
    if (x >= PW) return;
    int y = blockIdx.x;       // 0..232
    int pl = blockIdx.y;      // 0..95
    int iy = y - 3;
    bool yok = (unsigned)iy < 224u;
    const float* src = inp + (size_t)pl * 50176 + iy * 224;
    float vA = (yok && (unsigned)(x - 3) < 224u) ? src[x - 3] : 0.f;
    float vB = (yok && (unsigned)(x - 2) < 224u) ? src[x - 2] : 0.f;
    size_t o = (size_t)pl * PPL + y * PW + x;
    padA[o] = f2bf(vA);
    padB[o] = f2bf(vB);
}

// ---------------------------------------------------------------------------
// conv1 via MFMA. Wave = 64 oc x 32 px; block = 4 waves x 32 px = 128 px,
// ALL on the same 64-oc A-slice (24 KB, L1-resident). oc-half = blockIdx.x&1.
__global__ __launch_bounds__(256, 4) void k_conv1m(const short* __restrict__ padA,
                                                   const short* __restrict__ padB,
                                                   const short* __restrict__ w1b,
                                                   const int2* __restrict__ map,
                                                   short* __restrict__ out1b,
                                                   float* __restrict__ sum1x,
                                                   float* __restrict__ sq1x) {
    __shared__ float sred[4][64][2];   // 2 KB
    int tid = threadIdx.x;
    int wave = tid >> 6, lane = tid & 63;
    int q = lane >> 4, l16 = lane & 15;
    int ochalf = blockIdx.x & 1;
    int pxblk = blockIdx.x >> 1;                      // 0..97
    int n = blockIdx.y;
    int px0 = pxblk * 128 + wave * 32 + l16;
    int px1 = px0 + 16;
    int2 m0 = map[px0];
    int2 m1 = map[px1];
    size_t bn = (size_t)n * 3 * PPL;
    const short* r0 = ((m0.y & 1) ? padB + (m0.y - 1) : padA + m0.y) + bn + m0.x * PW;
    const short* r1 = ((m1.y & 1) ? padB + (m1.y - 1) : padA + m1.y) + bn + m1.x * PW;

    bf16x8 ld[12];
#pragma unroll
    for (int icc = 0; icc < 6; icc++) {
        int g8 = (icc == 5) ? 20 : (icc * 4 + q);
        int ic = (g8 >= 7) + (g8 >= 14);
        int ky = g8 - ic * 7;
        int off = ic * PPL + ky * PW;
        ld[icc * 2]     = ldb8(r0 + off);
        ld[icc * 2 + 1] = ldb8(r1 + off);
    }

    f32x4 acc[4][2];
#pragma unroll
    for (int t = 0; t < 4; t++) { acc[t][0] = (f32x4){0,0,0,0}; acc[t][1] = (f32x4){0,0,0,0}; }

    const short* wb = w1b + (ochalf * 64 + l16) * K1C + q * 8;
#pragma unroll
    for (int icc = 0; icc < 6; icc++) {
        bf16x8 bf0 = ld[icc * 2];
        bf16x8 bf1 = ld[icc * 2 + 1];
        const short* wk = wb + icc * 32;
#pragma unroll
        for (int t = 0; t < 4; t++) {
            bf16x8 af = *(const bf16x8*)(wk + t * 16 * K1C);
            acc[t][0] = __builtin_amdgcn_mfma_f32_16x16x32_bf16(af, bf0, acc[t][0], 0, 0, 0);
            acc[t][1] = __builtin_amdgcn_mfma_f32_16x16x32_bf16(af, bf1, acc[t][1], 0, 0, 0);
        }
    }

    // epilogue: C layout col(px)=l16, row(oc_local)=q*4+r ; store NHWC bf16
    short* ob = out1b + ((size_t)(n * PIX1) + px0) * OCN + ochalf * 64 + q * 4;
#pragma unroll
    for (int t = 0; t < 4; t++) {
#pragma unroll
        for (int g = 0; g < 2; g++) {
            f32x4 a = acc[t][g];
            uint2 u;
            u.x = pack2bf(a[0], a[1]);
            u.y = pack2bf(a[2], a[3]);
            *(uint2*)(ob + (size_t)g * 16 * OCN + t * 16) = u;
        }
    }

    // fused BN1 stats: shuffle-reduce 16 px-lanes -> LDS -> block pass
#pragma unroll
    for (int t = 0; t < 4; t++) {
#pragma unroll
        for (int r = 0; r < 4; r++) {
            float a0 = acc[t][0][r], a1 = acc[t][1][r];
            float s = a0 + a1;
            float z = fmaf(a0, a0, a1 * a1);
#pragma unroll
            for (int msk = 1; msk < 16; msk <<= 1) {
                s += __shfl_xor(s, msk, 64);
                z += __shfl_xor(z, msk, 64);
            }
            if (l16 == 0) {
                int ocl = t * 16 + q * 4 + r;     // 0..63
                sred[wave][ocl][0] = s;
                sred[wave][ocl][1] = z;
            }
        }
    }
    __syncthreads();
    if (tid < 64) {
        float s = sred[0][tid][0] + sred[1][tid][0] + sred[2][tid][0] + sred[3][tid][0];
        float z = sred[0][tid][1] + sred[1][tid][1] + sred[2][tid][1] + sred[3][tid][1];
        int oc = ochalf * 64 + tid;
        atomicAdd(&sum1x[n * OCN + oc], s);
        atomicAdd(&sq1x[n * OCN + oc], z);
    }
}

// ---------------------------------------------------------------------------
// Finalize BN params from per-n partial sums: 32x128 -> scale/shift.
__global__ void k_fin2(const float* __restrict__ sumx, const float* __restrict__ sqx,
                       const float* __restrict__ gamma, const float* __restrict__ beta,
                       float invN, float* __restrict__ scale, float* __restrict__ shift) {
    int c = threadIdx.x;
    if (c >= OCN) return;
    float s = 0.f, q = 0.f;
    for (int n = 0; n < BN_; n++) { s += sumx[n * OCN + c]; q += sqx[n * OCN + c]; }
    float m = s * invN;
    float v = q * invN - m * m;
    float sc = gamma[c] * rsqrtf(v + 1e-5f);
    scale[c] = sc;
    shift[c] = beta[c] - m * sc;
}

// ---------------------------------------------------------------------------
// BN1 affine + 3x3/2 maxpool + ReLU: NHWC bf16 (112x112) -> padded NHWC bf16 (58x58)
__global__ __launch_bounds__(256) void k_bnpool(const unsigned* __restrict__ out1b,
                                                const float* __restrict__ scale,
                                                const float* __restrict__ shift,
                                                unsigned* __restrict__ h2p) {
    int tid = threadIdx.x;
    int c2 = tid & 63, po = tid >> 6;
    int pp = blockIdx.x * 4 + po;
    int n = blockIdx.y;
    int py = pp / POOLSZ, px = pp % POOLSZ;
    const unsigned* base = out1b + (size_t)n * PIX1 * 64;
    float sc0 = scale[2 * c2],     sh0 = shift[2 * c2];
    float sc1 = scale[2 * c2 + 1], sh1 = shift[2 * c2 + 1];
    float m0 = -1e30f, m1 = -1e30f;
#pragma unroll
    for (int dy = 0; dy < 3; dy++) {
        int y = 2 * py - 1 + dy;
        if ((unsigned)y >= (unsigned)OUTSZ) continue;
#pragma unroll
        for (int dx = 0; dx < 3; dx++) {
            int x = 2 * px - 1 + dx;
            if ((unsigned)x >= (unsigned)OUTSZ) continue;
            unsigned u = base[(size_t)(y * OUTSZ + x) * 64 + c2];
            float v0 = __uint_as_float(u << 16);
            float v1 = __uint_as_float(u & 0xffff0000u);
            m0 = fmaxf(m0, fmaf(sc0, v0, sh0));
            m1 = fmaxf(m1, fmaf(sc1, v1, sh1));
        }
    }
    m0 = fmaxf(m0, 0.f); m1 = fmaxf(m1, 0.f);
    h2p[(size_t)n * (HSTRIDE / 2) + ((py + 1) * HP + (px + 1)) * 64 + c2] = pack2bf(m0, m1);
}

// ---------------------------------------------------------------------------
// conv2 via bf16 MFMA. Wave = 128 oc x 64 px, block = 4 waves = 256 px
// (R10 tile). XCD-aware swizzle: 416 blocks 1-D; block id -> XCD = id&7;
// each XCD serves 4 n-slices (4 x 861 KB < 4 MB L2) so B stays L2-resident.
// Flattened 36-step (s,icc) loop with 2-deep B-fragment prefetch ring.
__global__ __launch_bounds__(256, 2) void k_conv2m(const short* __restrict__ h2p,
                                                   const short* __restrict__ w2b,
                                                   short* __restrict__ out2b,
                                                   float* __restrict__ sum2x,
                                                   float* __restrict__ sq2x) {
    __shared__ float sred[4][OCN][2];
    int tid = threadIdx.x;
    int wave = tid >> 6, lane = tid & 63;
    int q = lane >> 4, l16 = lane & 15;
    int id = blockIdx.x;              // 0..415
    int xcd = id & 7;
    int seq = id >> 3;                // 0..51
    int n = xcd + 8 * (seq / 13);
    int pxblk = seq % 13;
    int pxb = pxblk * 256 + wave * 64 + l16;
    bool st[4];
    int bofs[4];
#pragma unroll
    for (int g = 0; g < 4; g++) {
        int p = pxb + g * 16;
        st[g] = p < PIX2;
        int pc = st[g] ? p : (PIX2 - 1);
        int y = pc / POOLSZ, x = pc % POOLSZ;
        bofs[g] = (y * HP + x) * OCN;
    }
    const short* hb = h2p + (size_t)n * HSTRIDE;

    f32x4 acc[8][4];
#pragma unroll
    for (int t = 0; t < 8; t++)
#pragma unroll
        for (int g = 0; g < 4; g++) acc[t][g] = (f32x4){0, 0, 0, 0};

    // B prefetch ring: step j = (s,icc) = (j/4, j%4)
    bf16x8 bbuf[3][4];
#pragma unroll
    for (int j0 = 0; j0 < 2; j0++) {
        int off0 = ((j0 / 4) / 3 * HP + (j0 / 4) % 3) * OCN + (j0 % 4) * 32 + q * 8;
#pragma unroll
        for (int g = 0; g < 4; g++) bbuf[j0][g] = ldb8(hb + bofs[g] + off0);
    }
#pragma unroll
    for (int j = 0; j < 36; j++) {
        if (j + 2 < 36) {
            int jn = j + 2;
            int offn = ((jn / 4) / 3 * HP + (jn / 4) % 3) * OCN + (jn % 4) * 32 + q * 8;
#pragma unroll
            for (int g = 0; g < 4; g++) bbuf[jn % 3][g] = ldb8(hb + bofs[g] + offn);
        }
        const short* wbase = w2b + ((j / 4) * OCN + l16) * OCN + (j % 4) * 32 + q * 8;
#pragma unroll
        for (int t = 0; t < 8; t++) {
            bf16x8 af = *(const bf16x8*)(wbase + t * 16 * OCN);
#pragma unroll
            for (int g = 0; g < 4; g++)
                acc[t][g] = __builtin_amdgcn_mfma_f32_16x16x32_bf16(af, bbuf[j % 3][g], acc[t][g], 0, 0, 0);
        }
    }
    // C/D layout: col(px)=l16, row(oc)=q*4+reg ; store NCHW bf16
    short* on = out2b + (size_t)n * OCN * PIX2;
#pragma unroll
    for (int t = 0; t < 8; t++) {
        int ocb = t * 16 + q * 4;
#pragma unroll
        for (int g = 0; g < 4; g++) {
            if (!st[g]) continue;
            int p = pxb + g * 16;
#pragma unroll
            for (int r = 0; r < 4; r++)
                on[(size_t)(ocb + r) * PIX2 + p] = f2bf(acc[t][g][r]);
        }
    }
    // fused BN2 stats (every wave writes sred; masked groups contribute 0)
#pragma unroll
    for (int t = 0; t < 8; t++) {
#pragma unroll
        for (int r = 0; r < 4; r++) {
            float s = 0.f, z = 0.f;
#pragma unroll
            for (int g = 0; g < 4; g++) {
                if (!st[g]) continue;
                float v = acc[t][g][r];
                s += v;
                z = fmaf(v, v, z);
            }
#pragma unroll
            for (int msk = 1; msk < 16; msk <<= 1) {
                s += __shfl_xor(s, msk, 64);
                z += __shfl_xor(z, msk, 64);
            }
            if (l16 == 0) {
                int oc = t * 16 + q * 4 + r;
                sred[wave][oc][0] = s;
                sred[wave][oc][1] = z;
            }
        }
    }
    __syncthreads();
    if (tid < OCN) {
        float s = sred[0][tid][0] + sred[1][tid][0] + sred[2][tid][0] + sred[3][tid][0];
        float z = sred[0][tid][1] + sred[1][tid][1] + sred[2][tid][1] + sred[3][tid][1];
        atomicAdd(&sum2x[n * OCN + tid], s);
        atomicAdd(&sq2x[n * OCN + tid], z);
    }
}

// BN2 affine + ReLU: NCHW bf16 temp -> fp32 d_out. 2 px per thread.
__global__ __launch_bounds__(256) void k_bnrelu(const unsigned* __restrict__ in2,
                                                float* __restrict__ y,
                                                const float* __restrict__ scale,
                                                const float* __restrict__ shift) {
    size_t i2 = (size_t)blockIdx.x * 256 + threadIdx.x;   // 25088*256 = 6,422,528 exact
    int c = (int)((i2 / (PIX2 / 2)) & (OCN - 1));
    unsigned u = in2[i2];
    float v0 = __uint_as_float(u << 16);
    float v1 = __uint_as_float(u & 0xffff0000u);
    float sc = scale[c], sh = shift[c];
    float2 o;
    o.x = fmaxf(fmaf(sc, v0, sh), 0.f);
    o.y = fmaxf(fmaf(sc, v1, sh), 0.f);
    *(float2*)(y + 2 * i2) = o;
}

// ---------------------------------------------------------------------------
extern "C" void kernel_launch(void* const* d_in, const int* in_sizes, int n_in,
                              void* d_out, int out_size, void* d_ws, size_t ws_size,
                              hipStream_t stream) {
    const float* inp = (const float*)d_in[0];
    const float* w1  = (const float*)d_in[1];
    const float* g1  = (const float*)d_in[2];
    const float* b1  = (const float*)d_in[3];
    const float* w2  = (const float*)d_in[4];
    const float* g2  = (const float*)d_in[5];
    const float* b2  = (const float*)d_in[6];
    float* out = (float*)d_out;

    char* ws = (char*)d_ws;
    int2*  map   = (int2*)ws;                         // 100,352 B
    float* stats = (float*)(ws + 102400);             // 65,536 B zeroed in k_setup
    short* w2b   = (short*)(ws + 176128);             // 294,912 B -> 471,040
    short* w1b   = (short*)(ws + 471040);             // 49,152 B  -> 520,192
    short* padA  = (short*)(ws + 520192);             // 10,736,640 B -> 11,256,832
    short* padB  = (short*)(ws + 11256832ULL);        // 10,736,640 B -> 21,993,472
    short* h2p   = (short*)(ws + 21993472ULL);        // 27,557,888 B -> 49,551,360
    short* out1b = (short*)(ws + 49551360ULL);        // 102,760,448 B -> 152,311,808
    short* out2b = (short*)(ws + 152311808ULL);       // 25,690,112 B -> 178,001,920

    float* sum1x = stats;                // 32*128
    float* sq1x  = stats + 4096;
    float* sum2x = stats + 8192;
    float* sq2x  = stats + 12288;
    // BN param slots written by k_fin2 before any reader; zero-init not needed.
    float* SC1 = stats + 16384, *SH1 = stats + 16512;
    float* SC2 = stats + 16640, *SH2 = stats + 16768;

    k_setup <<<dim3(2609), 256, 0, stream>>>(w1, w1b, w2, w2b, map, stats, (unsigned*)h2p);
    k_pad   <<<dim3(PH, 96), 256, 0, stream>>>(inp, padA, padB);
    k_conv1m<<<dim3(196, BN_), 256, 0, stream>>>(padA, padB, w1b, map, out1b, sum1x, sq1x);
    k_fin2  <<<1, 128, 0, stream>>>(sum1x, sq1x, g1, b1, 1.f / (BN_ * PIX1), SC1, SH1);
    k_bnpool<<<dim3(PIX2 / 4, BN_), 256, 0, stream>>>((const unsigned*)out1b, SC1, SH1, (unsigned*)h2p);
    k_conv2m<<<dim3(416), 256, 0, stream>>>(h2p, w2b, out2b, sum2x, sq2x);
    k_fin2  <<<1, 128, 0, stream>>>(sum2x, sq2x, g2, b2, 1.f / (BN_ * PIX2), SC2, SH2);
    k_bnrelu<<<dim3(25088), 256, 0, stream>>>((const unsigned*)out2b, out, SC2, SH2);
}

// Round 13
// 347.346 us; speedup vs baseline: 1.1474x; 1.0590x over previous
//
#include <hip/hip_runtime.h>
#include <hip/hip_bf16.h>
#include <cstdint>

// ---------------------------------------------------------------------------
#define IMGSZ 224
#define OUTSZ 112
#define POOLSZ 56
#define OCN 128
#define BN_ 32
#define PIX1 (OUTSZ*OUTSZ)     // 12544
#define PIX2 (POOLSZ*POOLSZ)   // 3136
#define HP 58                  // padded pooled dim (56 + 2)
#define HSTRIDE (HP*HP*OCN)    // elems per n in h2p
#define PW 240                 // padded input row stride (x in [-3,236))
#define PH 233                 // padded input rows (y in [-3,230))
#define PPL (PH*PW)            // 55920 elems per padded plane
#define K1C 192                // conv1 K: 24 groups of 8 = (ic*7+ky)*8+kx layout

typedef float f32x4 __attribute__((ext_vector_type(4)));
typedef short bf16x8 __attribute__((ext_vector_type(8)));
struct alignas(4) u4a { unsigned x, y, z, w; };   // 4B-aligned 16B load

__device__ inline short f2bf(float v) {
    __hip_bfloat16 h = __float2bfloat16(v);
    return *(short*)&h;
}
__device__ inline unsigned pack2bf(float a, float b) {
    return (unsigned short)f2bf(a) | ((unsigned)(unsigned short)f2bf(b) << 16);
}
__device__ inline bf16x8 ldb8(const short* p) {   // 16B load, 4B-aligned
    u4a t = *(const u4a*)p;
    union { u4a u; bf16x8 v; } c; c.u = t; return c.v;
}

// ---------------------------------------------------------------------------
// Fused setup: [0,49) map ; [49,145) wpack1 ; [145,721) wconv ;
// [721,785) stats zero ; [785,2609) h2p halo zero.
__global__ __launch_bounds__(256) void k_setup(const float* __restrict__ w1,
                                               short* __restrict__ w1b,
                                               const float* __restrict__ w2,
                                               short* __restrict__ w2b,
                                               int2* __restrict__ map,
                                               float* __restrict__ stats,
                                               unsigned* __restrict__ h2p) {
    int blk = blockIdx.x;
    int tid = threadIdx.x;
    if (blk < 49) {
        int p = blk * 256 + tid;
        int oy = p / OUTSZ, ox = p % OUTSZ;
        int e = min(min(oy, ox), min(111 - oy, 111 - ox));
        int s = e >> 3;
        int a = 16 * s, b = a + 16, c = 224 - b, d = 224 - a;
        int ao = a >> 1, bo = b >> 1, co = c >> 1, dd = d >> 1;
        int ti, li, bi, ri;
        if      (oy >= ao && oy < bo && ox >= ao && ox < co) { ti=a; li=a; bi=b; ri=c; }
        else if (oy >= bo && oy < dd && ox >= ao && ox < bo) { ti=b; li=a; bi=d; ri=b; }
        else if (oy >= co && oy < dd && ox >= bo && ox < dd) { ti=c; li=b; bi=d; ri=d; }
        else                                                 { ti=a; li=c; bi=c; ri=d; }
        float scale = (float)(2.0 - (double)s * 0.16666666666666666);
        int tip = (int)((float)(ti + 6) / scale) - 3;
        int lip = (int)((float)(li + 6) / scale) - 3;
        int bip = (int)((float)(bi + 6) / scale) + 3;
        int rip = (int)((float)(ri + 6) / scale) + 3;
        int fh = (bip - tip - 7) / 2 + 1;
        int fw = (rip - lip - 7) / 2 + 1;
        int to = ti >> 1, lo = li >> 1, bo2 = bi >> 1, ro = ri >> 1;
        int i = oy - to, j = ox - lo;
        int pp = (i * fh) / (bo2 - to);
        int qq = (j * fw) / (ro - lo);
        map[p] = make_int2(tip + 2 * pp, lip + 2 * qq);
    } else if (blk < 145) {
        int idx = (blk - 49) * 256 + tid;
        int oc = idx / K1C, k = idx % K1C;
        int g8 = k >> 3, e2 = k & 7;
        float v = 0.f;
        if (g8 < 21 && e2 < 7) {
            int ic = g8 / 7, ky = g8 - ic * 7;
            v = w1[((oc * 3 + ic) * 7 + ky) * 7 + e2];
        }
        w1b[idx] = f2bf(v);
    } else if (blk < 721) {
        int idx = (blk - 145) * 256 + tid;
        int s = idx % 9;
        int t = idx / 9;
        int ic = t & 127;
        int oc = t >> 7;
        w2b[(s * OCN + oc) * OCN + ic] = f2bf(w2[idx]);
    } else if (blk < 785) {
        stats[(blk - 721) * 256 + tid] = 0.f;
    } else {
        int idx = blk - 785;                  // 0..1823
        int bx = idx % 57, n = idx / 57;
        int c2 = tid & 63, po = tid >> 6;
        int pp = bx * 4 + po;                 // 0..227
        int y, x;
        if      (pp < 58)  { y = 0;  x = pp; }
        else if (pp < 116) { y = 57; x = pp - 58; }
        else if (pp < 172) { y = pp - 116 + 1; x = 0; }
        else               { y = pp - 172 + 1; x = 57; }
        h2p[(size_t)n * (HSTRIDE / 2) + (y * HP + x) * 64 + c2] = 0u;
    }
}

// ---------------------------------------------------------------------------
// Zero-haloed padded bf16 input, TWO copies: padA[x] = img[x-3], padB[x] = img[x-2]
__global__ __launch_bounds__(256) void k_pad(const float* __restrict__ inp,
                                             short* __restrict__ padA,
                                             short* __restrict__ padB) {
    int x = threadIdx.x;
    if (x >= PW) return;
    int y = blockIdx.x;       // 0..232
    int pl = blockIdx.y;      // 0..95
    int iy = y - 3;
    bool yok = (unsigned)iy < 224u;
    const float* src = inp + (size_t)pl * 50176 + iy * 224;
    float vA = (yok && (unsigned)(x - 3) < 224u) ? src[x - 3] : 0.f;
    float vB = (yok && (unsigned)(x - 2) < 224u) ? src[x - 2] : 0.f;
    size_t o = (size_t)pl * PPL + y * PW + x;
    padA[o] = f2bf(vA);
    padB[o] = f2bf(vB);
}

// ---------------------------------------------------------------------------
// conv1 via MFMA. Wave = 64 oc x 32 px; block = 4 waves x 32 px = 128 px,
// ALL on the same 64-oc A-slice (24 KB, L1-resident). oc-half = blockIdx.x&1.
__global__ __launch_bounds__(256, 4) void k_conv1m(const short* __restrict__ padA,
                                                   const short* __restrict__ padB,
                                                   const short* __restrict__ w1b,
                                                   const int2* __restrict__ map,
                                                   short* __restrict__ out1b,
                                                   float* __restrict__ sum1x,
                                                   float* __restrict__ sq1x) {
    __shared__ float sred[4][64][2];   // 2 KB
    int tid = threadIdx.x;
    int wave = tid >> 6, lane = tid & 63;
    int q = lane >> 4, l16 = lane & 15;
    int ochalf = blockIdx.x & 1;
    int pxblk = blockIdx.x >> 1;                      // 0..97
    int n = blockIdx.y;
    int px0 = pxblk * 128 + wave * 32 + l16;
    int px1 = px0 + 16;
    int2 m0 = map[px0];
    int2 m1 = map[px1];
    size_t bn = (size_t)n * 3 * PPL;
    const short* r0 = ((m0.y & 1) ? padB + (m0.y - 1) : padA + m0.y) + bn + m0.x * PW;
    const short* r1 = ((m1.y & 1) ? padB + (m1.y - 1) : padA + m1.y) + bn + m1.x * PW;

    bf16x8 ld[12];
#pragma unroll
    for (int icc = 0; icc < 6; icc++) {
        int g8 = (icc == 5) ? 20 : (icc * 4 + q);
        int ic = (g8 >= 7) + (g8 >= 14);
        int ky = g8 - ic * 7;
        int off = ic * PPL + ky * PW;
        ld[icc * 2]     = ldb8(r0 + off);
        ld[icc * 2 + 1] = ldb8(r1 + off);
    }

    f32x4 acc[4][2];
#pragma unroll
    for (int t = 0; t < 4; t++) { acc[t][0] = (f32x4){0,0,0,0}; acc[t][1] = (f32x4){0,0,0,0}; }

    const short* wb = w1b + (ochalf * 64 + l16) * K1C + q * 8;
#pragma unroll
    for (int icc = 0; icc < 6; icc++) {
        bf16x8 bf0 = ld[icc * 2];
        bf16x8 bf1 = ld[icc * 2 + 1];
        const short* wk = wb + icc * 32;
#pragma unroll
        for (int t = 0; t < 4; t++) {
            bf16x8 af = *(const bf16x8*)(wk + t * 16 * K1C);
            acc[t][0] = __builtin_amdgcn_mfma_f32_16x16x32_bf16(af, bf0, acc[t][0], 0, 0, 0);
            acc[t][1] = __builtin_amdgcn_mfma_f32_16x16x32_bf16(af, bf1, acc[t][1], 0, 0, 0);
        }
    }

    // epilogue: C layout col(px)=l16, row(oc_local)=q*4+r ; store NHWC bf16
    short* ob = out1b + ((size_t)(n * PIX1) + px0) * OCN + ochalf * 64 + q * 4;
#pragma unroll
    for (int t = 0; t < 4; t++) {
#pragma unroll
        for (int g = 0; g < 2; g++) {
            f32x4 a = acc[t][g];
            uint2 u;
            u.x = pack2bf(a[0], a[1]);
            u.y = pack2bf(a[2], a[3]);
            *(uint2*)(ob + (size_t)g * 16 * OCN + t * 16) = u;
        }
    }

    // fused BN1 stats: shuffle-reduce 16 px-lanes -> LDS -> block pass
#pragma unroll
    for (int t = 0; t < 4; t++) {
#pragma unroll
        for (int r = 0; r < 4; r++) {
            float a0 = acc[t][0][r], a1 = acc[t][1][r];
            float s = a0 + a1;
            float z = fmaf(a0, a0, a1 * a1);
#pragma unroll
            for (int msk = 1; msk < 16; msk <<= 1) {
                s += __shfl_xor(s, msk, 64);
                z += __shfl_xor(z, msk, 64);
            }
            if (l16 == 0) {
                int ocl = t * 16 + q * 4 + r;     // 0..63
                sred[wave][ocl][0] = s;
                sred[wave][ocl][1] = z;
            }
        }
    }
    __syncthreads();
    if (tid < 64) {
        float s = sred[0][tid][0] + sred[1][tid][0] + sred[2][tid][0] + sred[3][tid][0];
        float z = sred[0][tid][1] + sred[1][tid][1] + sred[2][tid][1] + sred[3][tid][1];
        int oc = ochalf * 64 + tid;
        atomicAdd(&sum1x[n * OCN + oc], s);
        atomicAdd(&sq1x[n * OCN + oc], z);
    }
}

// ---------------------------------------------------------------------------
// Finalize BN params from per-n partial sums: 32x128 -> scale/shift.
__global__ void k_fin2(const float* __restrict__ sumx, const float* __restrict__ sqx,
                       const float* __restrict__ gamma, const float* __restrict__ beta,
                       float invN, float* __restrict__ scale, float* __restrict__ shift) {
    int c = threadIdx.x;
    if (c >= OCN) return;
    float s = 0.f, q = 0.f;
    for (int n = 0; n < BN_; n++) { s += sumx[n * OCN + c]; q += sqx[n * OCN + c]; }
    float m = s * invN;
    float v = q * invN - m * m;
    float sc = gamma[c] * rsqrtf(v + 1e-5f);
    scale[c] = sc;
    shift[c] = beta[c] - m * sc;
}

// ---------------------------------------------------------------------------
// BN1 affine + 3x3/2 maxpool + ReLU: NHWC bf16 (112x112) -> padded NHWC bf16 (58x58)
__global__ __launch_bounds__(256) void k_bnpool(const unsigned* __restrict__ out1b,
                                                const float* __restrict__ scale,
                                                const float* __restrict__ shift,
                                                unsigned* __restrict__ h2p) {
    int tid = threadIdx.x;
    int c2 = tid & 63, po = tid >> 6;
    int pp = blockIdx.x * 4 + po;
    int n = blockIdx.y;
    int py = pp / POOLSZ, px = pp % POOLSZ;
    const unsigned* base = out1b + (size_t)n * PIX1 * 64;
    float sc0 = scale[2 * c2],     sh0 = shift[2 * c2];
    float sc1 = scale[2 * c2 + 1], sh1 = shift[2 * c2 + 1];
    float m0 = -1e30f, m1 = -1e30f;
#pragma unroll
    for (int dy = 0; dy < 3; dy++) {
        int y = 2 * py - 1 + dy;
        if ((unsigned)y >= (unsigned)OUTSZ) continue;
#pragma unroll
        for (int dx = 0; dx < 3; dx++) {
            int x = 2 * px - 1 + dx;
            if ((unsigned)x >= (unsigned)OUTSZ) continue;
            unsigned u = base[(size_t)(y * OUTSZ + x) * 64 + c2];
            float v0 = __uint_as_float(u << 16);
            float v1 = __uint_as_float(u & 0xffff0000u);
            m0 = fmaxf(m0, fmaf(sc0, v0, sh0));
            m1 = fmaxf(m1, fmaf(sc1, v1, sh1));
        }
    }
    m0 = fmaxf(m0, 0.f); m1 = fmaxf(m1, 0.f);
    h2p[(size_t)n * (HSTRIDE / 2) + ((py + 1) * HP + (px + 1)) * 64 + c2] = pack2bf(m0, m1);
}

// ---------------------------------------------------------------------------
// conv2 via bf16 MFMA. Wave = 128 oc x 64 px, block = 4 waves = 256 px.
// XCD-aware swizzle (B L2-resident per XCD). A (weights) staged per-s in LDS:
// 32 KB slice, 16B-column XOR swizzle, next slice's global loads issued into
// registers during current compute (latency hidden). B: 2-deep prefetch ring.
__global__ __launch_bounds__(256, 2) void k_conv2m(const short* __restrict__ h2p,
                                                   const short* __restrict__ w2b,
                                                   short* __restrict__ out2b,
                                                   float* __restrict__ sum2x,
                                                   float* __restrict__ sq2x) {
    __shared__ short As[128 * 128];      // 32 KB A-slice, swizzled
    __shared__ float sred[4][OCN][2];    // 4 KB
    int tid = threadIdx.x;
    int wave = tid >> 6, lane = tid & 63;
    int q = lane >> 4, l16 = lane & 15;
    int id = blockIdx.x;              // 0..415
    int xcd = id & 7;
    int seq = id >> 3;                // 0..51
    int n = xcd + 8 * (seq / 13);
    int pxblk = seq % 13;
    int pxb = pxblk * 256 + wave * 64 + l16;
    bool st[4];
    int bofs[4];
#pragma unroll
    for (int g = 0; g < 4; g++) {
        int p = pxb + g * 16;
        st[g] = p < PIX2;
        int pc = st[g] ? p : (PIX2 - 1);
        int y = pc / POOLSZ, x = pc % POOLSZ;
        bofs[g] = (y * HP + x) * OCN;
    }
    const short* hb = h2p + (size_t)n * HSTRIDE;

    // A staging helpers: thread tid handles chunks tid + i*256 (oc = chunk>>4,
    // col = chunk&15); LDS column swizzled by oc&15.
    int a_oc[8], a_colx[8];
#pragma unroll
    for (int i = 0; i < 8; i++) {
        int chunk = tid + i * 256;
        a_oc[i] = chunk >> 4;
        int col = chunk & 15;
        a_colx[i] = (col ^ (a_oc[i] & 15)) * 8;
    }

    u4a areg[8];
#pragma unroll
    for (int i = 0; i < 8; i++)
        areg[i] = *(const u4a*)(w2b + a_oc[i] * OCN + (tid & 15) * 8);   // s=0 slice

    f32x4 acc[8][4];
#pragma unroll
    for (int t = 0; t < 8; t++)
#pragma unroll
        for (int g = 0; g < 4; g++) acc[t][g] = (f32x4){0, 0, 0, 0};

    // B prefetch ring: step j = (s,icc) = (j/4, j%4)
    bf16x8 bbuf[3][4];
#pragma unroll
    for (int j0 = 0; j0 < 2; j0++) {
        int off0 = ((j0 / 4) / 3 * HP + (j0 / 4) % 3) * OCN + (j0 % 4) * 32 + q * 8;
#pragma unroll
        for (int g = 0; g < 4; g++) bbuf[j0][g] = ldb8(hb + bofs[g] + off0);
    }

    // write s=0 slice to LDS
#pragma unroll
    for (int i = 0; i < 8; i++)
        *(u4a*)(As + a_oc[i] * 128 + a_colx[i]) = areg[i];
    __syncthreads();

    const short* Abase = As + l16 * 128;     // + t*2048 + swizzled col
    for (int s = 0; s < 9; s++) {
        if (s < 8) {
            const short* wns = w2b + (size_t)(s + 1) * 16384;
#pragma unroll
            for (int i = 0; i < 8; i++)
                areg[i] = *(const u4a*)(wns + a_oc[i] * OCN + (tid & 15) * 8);
        }
#pragma unroll
        for (int icc = 0; icc < 4; icc++) {
            int j = s * 4 + icc;
            int jn = j + 2; if (jn > 35) jn = 35;
            int offn = ((jn >> 2) / 3 * HP + (jn >> 2) % 3) * OCN + (jn & 3) * 32 + q * 8;
#pragma unroll
            for (int g = 0; g < 4; g++) bbuf[jn % 3][g] = ldb8(hb + bofs[g] + offn);
            int colx = ((icc * 4 + q) ^ l16) * 8;
#pragma unroll
            for (int t = 0; t < 8; t++) {
                bf16x8 af = *(const bf16x8*)(Abase + t * 2048 + colx);
#pragma unroll
                for (int g = 0; g < 4; g++)
                    acc[t][g] = __builtin_amdgcn_mfma_f32_16x16x32_bf16(af, bbuf[j % 3][g], acc[t][g], 0, 0, 0);
            }
        }
        if (s < 8) {
            __syncthreads();
#pragma unroll
            for (int i = 0; i < 8; i++)
                *(u4a*)(As + a_oc[i] * 128 + a_colx[i]) = areg[i];
            __syncthreads();
        }
    }
    // C/D layout: col(px)=l16, row(oc)=q*4+reg ; store NCHW bf16
    short* on = out2b + (size_t)n * OCN * PIX2;
#pragma unroll
    for (int t = 0; t < 8; t++) {
        int ocb = t * 16 + q * 4;
#pragma unroll
        for (int g = 0; g < 4; g++) {
            if (!st[g]) continue;
            int p = pxb + g * 16;
#pragma unroll
            for (int r = 0; r < 4; r++)
                on[(size_t)(ocb + r) * PIX2 + p] = f2bf(acc[t][g][r]);
        }
    }
    // fused BN2 stats (every wave writes sred; masked groups contribute 0)
#pragma unroll
    for (int t = 0; t < 8; t++) {
#pragma unroll
        for (int r = 0; r < 4; r++) {
            float s = 0.f, z = 0.f;
#pragma unroll
            for (int g = 0; g < 4; g++) {
                if (!st[g]) continue;
                float v = acc[t][g][r];
                s += v;
                z = fmaf(v, v, z);
            }
#pragma unroll
            for (int msk = 1; msk < 16; msk <<= 1) {
                s += __shfl_xor(s, msk, 64);
                z += __shfl_xor(z, msk, 64);
            }
            if (l16 == 0) {
                int oc = t * 16 + q * 4 + r;
                sred[wave][oc][0] = s;
                sred[wave][oc][1] = z;
            }
        }
    }
    __syncthreads();
    if (tid < OCN) {
        float s = sred[0][tid][0] + sred[1][tid][0] + sred[2][tid][0] + sred[3][tid][0];
        float z = sred[0][tid][1] + sred[1][tid][1] + sred[2][tid][1] + sred[3][tid][1];
        atomicAdd(&sum2x[n * OCN + tid], s);
        atomicAdd(&sq2x[n * OCN + tid], z);
    }
}

// BN2 affine + ReLU: NCHW bf16 temp -> fp32 d_out. 2 px per thread.
__global__ __launch_bounds__(256) void k_bnrelu(const unsigned* __restrict__ in2,
                                                float* __restrict__ y,
                                                const float* __restrict__ scale,
                                                const float* __restrict__ shift) {
    size_t i2 = (size_t)blockIdx.x * 256 + threadIdx.x;   // 25088*256 = 6,422,528 exact
    int c = (int)((i2 / (PIX2 / 2)) & (OCN - 1));
    unsigned u = in2[i2];
    float v0 = __uint_as_float(u << 16);
    float v1 = __uint_as_float(u & 0xffff0000u);
    float sc = scale[c], sh = shift[c];
    float2 o;
    o.x = fmaxf(fmaf(sc, v0, sh), 0.f);
    o.y = fmaxf(fmaf(sc, v1, sh), 0.f);
    *(float2*)(y + 2 * i2) = o;
}

// ---------------------------------------------------------------------------
extern "C" void kernel_launch(void* const* d_in, const int* in_sizes, int n_in,
                              void* d_out, int out_size, void* d_ws, size_t ws_size,
                              hipStream_t stream) {
    const float* inp = (const float*)d_in[0];
    const float* w1  = (const float*)d_in[1];
    const float* g1  = (const float*)d_in[2];
    const float* b1  = (const float*)d_in[3];
    const float* w2  = (const float*)d_in[4];
    const float* g2  = (const float*)d_in[5];
    const float* b2  = (const float*)d_in[6];
    float* out = (float*)d_out;

    char* ws = (char*)d_ws;
    int2*  map   = (int2*)ws;                         // 100,352 B
    float* stats = (float*)(ws + 102400);             // 65,536 B zeroed in k_setup
    short* w2b   = (short*)(ws + 176128);             // 294,912 B -> 471,040
    short* w1b   = (short*)(ws + 471040);             // 49,152 B  -> 520,192
    short* padA  = (short*)(ws + 520192);             // 10,736,640 B -> 11,256,832
    short* padB  = (short*)(ws + 11256832ULL);        // 10,736,640 B -> 21,993,472
    short* h2p   = (short*)(ws + 21993472ULL);        // 27,557,888 B -> 49,551,360
    short* out1b = (short*)(ws + 49551360ULL);        // 102,760,448 B -> 152,311,808
    short* out2b = (short*)(ws + 152311808ULL);       // 25,690,112 B -> 178,001,920

    float* sum1x = stats;                // 32*128
    float* sq1x  = stats + 4096;
    float* sum2x = stats + 8192;
    float* sq2x  = stats + 12288;
    // BN param slots written by k_fin2 before any reader; zero-init not needed.
    float* SC1 = stats + 16384, *SH1 = stats + 16512;
    float* SC2 = stats + 16640, *SH2 = stats + 16768;

    k_setup <<<dim3(2609), 256, 0, stream>>>(w1, w1b, w2, w2b, map, stats, (unsigned*)h2p);
    k_pad   <<<dim3(PH, 96), 256, 0, stream>>>(inp, padA, padB);
    k_conv1m<<<dim3(196, BN_), 256, 0, stream>>>(padA, padB, w1b, map, out1b, sum1x, sq1x);
    k_fin2  <<<1, 128, 0, stream>>>(sum1x, sq1x, g1, b1, 1.f / (BN_ * PIX1), SC1, SH1);
    k_bnpool<<<dim3(PIX2 / 4, BN_), 256, 0, stream>>>((const unsigned*)out1b, SC1, SH1, (unsigned*)h2p);
    k_conv2m<<<dim3(416), 256, 0, stream>>>(h2p, w2b, out2b, sum2x, sq2x);
    k_fin2  <<<1, 128, 0, stream>>>(sum2x, sq2x, g2, b2, 1.f / (BN_ * PIX2), SC2, SH2);
    k_bnrelu<<<dim3(25088), 256, 0, stream>>>((const unsigned*)out2b, out, SC2, SH2);
}

// Round 14
// 307.734 us; speedup vs baseline: 1.2952x; 1.1287x over previous
//
#include <hip/hip_runtime.h>
#include <hip/hip_bf16.h>
#include <cstdint>

// ---------------------------------------------------------------------------
#define IMGSZ 224
#define OUTSZ 112
#define POOLSZ 56
#define OCN 128
#define BN_ 32
#define PIX1 (OUTSZ*OUTSZ)     // 12544
#define PIX2 (POOLSZ*POOLSZ)   // 3136
#define HP 58                  // padded pooled dim (56 + 2)
#define HSTRIDE (HP*HP*OCN)    // elems per n in h2p
#define PW 240                 // padded input row stride (x in [-3,236))
#define PH 233                 // padded input rows (y in [-3,230))
#define PPL (PH*PW)            // 55920 elems per padded plane
#define K1C 192                // conv1 K: 24 groups of 8 = (ic*7+ky)*8+kx layout

typedef float f32x4 __attribute__((ext_vector_type(4)));
typedef short bf16x8 __attribute__((ext_vector_type(8)));
struct alignas(4) u4a { unsigned x, y, z, w; };   // 4B-aligned 16B load

__device__ inline short f2bf(float v) {
    __hip_bfloat16 h = __float2bfloat16(v);
    return *(short*)&h;
}
__device__ inline unsigned pack2bf(float a, float b) {
    return (unsigned short)f2bf(a) | ((unsigned)(unsigned short)f2bf(b) << 16);
}
__device__ inline bf16x8 ldb8(const short* p) {   // 16B load, 4B-aligned
    u4a t = *(const u4a*)p;
    union { u4a u; bf16x8 v; } c; c.u = t; return c.v;
}

// ---------------------------------------------------------------------------
// Fused setup: [0,49) map ; [49,145) wpack1 ; [145,721) wconv ;
// [721,785) stats zero ; [785,2609) h2p halo zero.
__global__ __launch_bounds__(256) void k_setup(const float* __restrict__ w1,
                                               short* __restrict__ w1b,
                                               const float* __restrict__ w2,
                                               short* __restrict__ w2b,
                                               int2* __restrict__ map,
                                               float* __restrict__ stats,
                                               unsigned* __restrict__ h2p) {
    int blk = blockIdx.x;
    int tid = threadIdx.x;
    if (blk < 49) {
        int p = blk * 256 + tid;
        int oy = p / OUTSZ, ox = p % OUTSZ;
        int e = min(min(oy, ox), min(111 - oy, 111 - ox));
        int s = e >> 3;
        int a = 16 * s, b = a + 16, c = 224 - b, d = 224 - a;
        int ao = a >> 1, bo = b >> 1, co = c >> 1, dd = d >> 1;
        int ti, li, bi, ri;
        if      (oy >= ao && oy < bo && ox >= ao && ox < co) { ti=a; li=a; bi=b; ri=c; }
        else if (oy >= bo && oy < dd && ox >= ao && ox < bo) { ti=b; li=a; bi=d; ri=b; }
        else if (oy >= co && oy < dd && ox >= bo && ox < dd) { ti=c; li=b; bi=d; ri=d; }
        else                                                 { ti=a; li=c; bi=c; ri=d; }
        float scale = (float)(2.0 - (double)s * 0.16666666666666666);
        int tip = (int)((float)(ti + 6) / scale) - 3;
        int lip = (int)((float)(li + 6) / scale) - 3;
        int bip = (int)((float)(bi + 6) / scale) + 3;
        int rip = (int)((float)(ri + 6) / scale) + 3;
        int fh = (bip - tip - 7) / 2 + 1;
        int fw = (rip - lip - 7) / 2 + 1;
        int to = ti >> 1, lo = li >> 1, bo2 = bi >> 1, ro = ri >> 1;
        int i = oy - to, j = ox - lo;
        int pp = (i * fh) / (bo2 - to);
        int qq = (j * fw) / (ro - lo);
        map[p] = make_int2(tip + 2 * pp, lip + 2 * qq);
    } else if (blk < 145) {
        int idx = (blk - 49) * 256 + tid;
        int oc = idx / K1C, k = idx % K1C;
        int g8 = k >> 3, e2 = k & 7;
        float v = 0.f;
        if (g8 < 21 && e2 < 7) {
            int ic = g8 / 7, ky = g8 - ic * 7;
            v = w1[((oc * 3 + ic) * 7 + ky) * 7 + e2];
        }
        w1b[idx] = f2bf(v);
    } else if (blk < 721) {
        int idx = (blk - 145) * 256 + tid;
        int s = idx % 9;
        int t = idx / 9;
        int ic = t & 127;
        int oc = t >> 7;
        w2b[(s * OCN + oc) * OCN + ic] = f2bf(w2[idx]);
    } else if (blk < 785) {
        stats[(blk - 721) * 256 + tid] = 0.f;
    } else {
        int idx = blk - 785;                  // 0..1823
        int bx = idx % 57, n = idx / 57;
        int c2 = tid & 63, po = tid >> 6;
        int pp = bx * 4 + po;                 // 0..227
        int y, x;
        if      (pp < 58)  { y = 0;  x = pp; }
        else if (pp < 116) { y = 57; x = pp - 58; }
        else if (pp < 172) { y = pp - 116 + 1; x = 0; }
        else               { y = pp - 172 + 1; x = 57; }
        h2p[(size_t)n * (HSTRIDE / 2) + (y * HP + x) * 64 + c2] = 0u;
    }
}

// ---------------------------------------------------------------------------
// Zero-haloed padded bf16 input, TWO copies: padA[x] = img[x-3], padB[x] = img[x-2]
__global__ __launch_bounds__(256) void k_pad(const float* __restrict__ inp,
                                             short* __restrict__ padA,
                                             short* __restrict__ padB) {
    int x = threadIdx.x;
    if (x >= PW) return;
    int y = blockIdx.x;       // 0..232
    int pl = blockIdx.y;      // 0..95
    int iy = y - 3;
    bool yok = (unsigned)iy < 224u;
    const float* src = inp + (size_t)pl * 50176 + iy * 224;
    float vA = (yok && (unsigned)(x - 3) < 224u) ? src[x - 3] : 0.f;
    float vB = (yok && (unsigned)(x - 2) < 224u) ? src[x - 2] : 0.f;
    size_t o = (size_t)pl * PPL + y * PW + x;
    padA[o] = f2bf(vA);
    padB[o] = f2bf(vB);
}

// ---------------------------------------------------------------------------
// conv1 via MFMA. Wave = 64 oc x 32 px; block = 4 waves x 32 px = 128 px,
// all on the same 64-oc A-slice. A staged ONCE in LDS (24 KB -> padded 32 KB,
// 16B-chunk XOR swizzle); B = 12 up-front global 16B loads per wave.
__global__ __launch_bounds__(256, 4) void k_conv1m(const short* __restrict__ padA,
                                                   const short* __restrict__ padB,
                                                   const short* __restrict__ w1b,
                                                   const int2* __restrict__ map,
                                                   short* __restrict__ out1b,
                                                   float* __restrict__ sum1x,
                                                   float* __restrict__ sq1x) {
    __shared__ short As[64 * 256];     // 32 KB: row r, 16B-chunk c at pos c^(r&15)
    __shared__ float sred[4][64][2];   // 2 KB
    int tid = threadIdx.x;
    int wave = tid >> 6, lane = tid & 63;
    int q = lane >> 4, l16 = lane & 15;
    int ochalf = blockIdx.x & 1;
    int pxblk = blockIdx.x >> 1;                      // 0..97
    int n = blockIdx.y;
    int px0 = pxblk * 128 + wave * 32 + l16;
    int px1 = px0 + 16;
    int2 m0 = map[px0];
    int2 m1 = map[px1];
    size_t bn = (size_t)n * 3 * PPL;
    const short* r0 = ((m0.y & 1) ? padB + (m0.y - 1) : padA + m0.y) + bn + m0.x * PW;
    const short* r1 = ((m1.y & 1) ? padB + (m1.y - 1) : padA + m1.y) + bn + m1.x * PW;

    // Stage A: 64 rows x 24 chunks of 16B = 1536 chunks; 6 per thread.
    const short* wsl = w1b + ochalf * 64 * K1C;
#pragma unroll
    for (int i = 0; i < 6; i++) {
        int chunk = tid + i * 256;
        int r = chunk / 24, c = chunk - r * 24;
        u4a v = *(const u4a*)(wsl + r * K1C + c * 8);
        *(u4a*)(As + r * 256 + ((c ^ (r & 15)) * 8)) = v;
    }

    // B loads (up-front, in-order consumption)
    bf16x8 ld[12];
#pragma unroll
    for (int icc = 0; icc < 6; icc++) {
        int g8 = (icc == 5) ? 20 : (icc * 4 + q);
        int ic = (g8 >= 7) + (g8 >= 14);
        int ky = g8 - ic * 7;
        int off = ic * PPL + ky * PW;
        ld[icc * 2]     = ldb8(r0 + off);
        ld[icc * 2 + 1] = ldb8(r1 + off);
    }

    f32x4 acc[4][2];
#pragma unroll
    for (int t = 0; t < 4; t++) { acc[t][0] = (f32x4){0,0,0,0}; acc[t][1] = (f32x4){0,0,0,0}; }

    __syncthreads();

    const short* Abase = As + l16 * 256;   // + t*16*256 + swizzled chunk
#pragma unroll
    for (int icc = 0; icc < 6; icc++) {
        bf16x8 bf0 = ld[icc * 2];
        bf16x8 bf1 = ld[icc * 2 + 1];
        int pos = ((icc * 4 + q) ^ l16) * 8;
#pragma unroll
        for (int t = 0; t < 4; t++) {
            bf16x8 af = *(const bf16x8*)(Abase + t * 16 * 256 + pos);
            acc[t][0] = __builtin_amdgcn_mfma_f32_16x16x32_bf16(af, bf0, acc[t][0], 0, 0, 0);
            acc[t][1] = __builtin_amdgcn_mfma_f32_16x16x32_bf16(af, bf1, acc[t][1], 0, 0, 0);
        }
    }

    // epilogue: C layout col(px)=l16, row(oc_local)=q*4+r ; store NHWC bf16
    short* ob = out1b + ((size_t)(n * PIX1) + px0) * OCN + ochalf * 64 + q * 4;
#pragma unroll
    for (int t = 0; t < 4; t++) {
#pragma unroll
        for (int g = 0; g < 2; g++) {
            f32x4 a = acc[t][g];
            uint2 u;
            u.x = pack2bf(a[0], a[1]);
            u.y = pack2bf(a[2], a[3]);
            *(uint2*)(ob + (size_t)g * 16 * OCN + t * 16) = u;
        }
    }

    // fused BN1 stats: shuffle-reduce 16 px-lanes -> LDS -> block pass
#pragma unroll
    for (int t = 0; t < 4; t++) {
#pragma unroll
        for (int r = 0; r < 4; r++) {
            float a0 = acc[t][0][r], a1 = acc[t][1][r];
            float s = a0 + a1;
            float z = fmaf(a0, a0, a1 * a1);
#pragma unroll
            for (int msk = 1; msk < 16; msk <<= 1) {
                s += __shfl_xor(s, msk, 64);
                z += __shfl_xor(z, msk, 64);
            }
            if (l16 == 0) {
                int ocl = t * 16 + q * 4 + r;     // 0..63
                sred[wave][ocl][0] = s;
                sred[wave][ocl][1] = z;
            }
        }
    }
    __syncthreads();
    if (tid < 64) {
        float s = sred[0][tid][0] + sred[1][tid][0] + sred[2][tid][0] + sred[3][tid][0];
        float z = sred[0][tid][1] + sred[1][tid][1] + sred[2][tid][1] + sred[3][tid][1];
        int oc = ochalf * 64 + tid;
        atomicAdd(&sum1x[n * OCN + oc], s);
        atomicAdd(&sq1x[n * OCN + oc], z);
    }
}

// ---------------------------------------------------------------------------
// Finalize BN params from per-n partial sums: 32x128 -> scale/shift.
__global__ void k_fin2(const float* __restrict__ sumx, const float* __restrict__ sqx,
                       const float* __restrict__ gamma, const float* __restrict__ beta,
                       float invN, float* __restrict__ scale, float* __restrict__ shift) {
    int c = threadIdx.x;
    if (c >= OCN) return;
    float s = 0.f, q = 0.f;
    for (int n = 0; n < BN_; n++) { s += sumx[n * OCN + c]; q += sqx[n * OCN + c]; }
    float m = s * invN;
    float v = q * invN - m * m;
    float sc = gamma[c] * rsqrtf(v + 1e-5f);
    scale[c] = sc;
    shift[c] = beta[c] - m * sc;
}

// ---------------------------------------------------------------------------
// BN1 affine + 3x3/2 maxpool + ReLU: NHWC bf16 (112x112) -> padded NHWC bf16 (58x58)
__global__ __launch_bounds__(256) void k_bnpool(const unsigned* __restrict__ out1b,
                                                const float* __restrict__ scale,
                                                const float* __restrict__ shift,
                                                unsigned* __restrict__ h2p) {
    int tid = threadIdx.x;
    int c2 = tid & 63, po = tid >> 6;
    int pp = blockIdx.x * 4 + po;
    int n = blockIdx.y;
    int py = pp / POOLSZ, px = pp % POOLSZ;
    const unsigned* base = out1b + (size_t)n * PIX1 * 64;
    float sc0 = scale[2 * c2],     sh0 = shift[2 * c2];
    float sc1 = scale[2 * c2 + 1], sh1 = shift[2 * c2 + 1];
    float m0 = -1e30f, m1 = -1e30f;
#pragma unroll
    for (int dy = 0; dy < 3; dy++) {
        int y = 2 * py - 1 + dy;
        if ((unsigned)y >= (unsigned)OUTSZ) continue;
#pragma unroll
        for (int dx = 0; dx < 3; dx++) {
            int x = 2 * px - 1 + dx;
            if ((unsigned)x >= (unsigned)OUTSZ) continue;
            unsigned u = base[(size_t)(y * OUTSZ + x) * 64 + c2];
            float v0 = __uint_as_float(u << 16);
            float v1 = __uint_as_float(u & 0xffff0000u);
            m0 = fmaxf(m0, fmaf(sc0, v0, sh0));
            m1 = fmaxf(m1, fmaf(sc1, v1, sh1));
        }
    }
    m0 = fmaxf(m0, 0.f); m1 = fmaxf(m1, 0.f);
    h2p[(size_t)n * (HSTRIDE / 2) + ((py + 1) * HP + (px + 1)) * 64 + c2] = pack2bf(m0, m1);
}

// ---------------------------------------------------------------------------
// conv2 via bf16 MFMA. Wave = 128 oc x 64 px, block = 4 waves = 256 px.
// XCD-aware swizzle (B L2-resident per XCD). A staged per-s in LDS (32 KB,
// XOR swizzle, next slice prefetched to regs during compute). B: 2-deep ring.
__global__ __launch_bounds__(256, 2) void k_conv2m(const short* __restrict__ h2p,
                                                   const short* __restrict__ w2b,
                                                   short* __restrict__ out2b,
                                                   float* __restrict__ sum2x,
                                                   float* __restrict__ sq2x) {
    __shared__ short As[128 * 128];      // 32 KB A-slice, swizzled
    __shared__ float sred[4][OCN][2];    // 4 KB
    int tid = threadIdx.x;
    int wave = tid >> 6, lane = tid & 63;
    int q = lane >> 4, l16 = lane & 15;
    int id = blockIdx.x;              // 0..415
    int xcd = id & 7;
    int seq = id >> 3;                // 0..51
    int n = xcd + 8 * (seq / 13);
    int pxblk = seq % 13;
    int pxb = pxblk * 256 + wave * 64 + l16;
    bool st[4];
    int bofs[4];
#pragma unroll
    for (int g = 0; g < 4; g++) {
        int p = pxb + g * 16;
        st[g] = p < PIX2;
        int pc = st[g] ? p : (PIX2 - 1);
        int y = pc / POOLSZ, x = pc % POOLSZ;
        bofs[g] = (y * HP + x) * OCN;
    }
    const short* hb = h2p + (size_t)n * HSTRIDE;

    int a_oc[8], a_colx[8];
#pragma unroll
    for (int i = 0; i < 8; i++) {
        int chunk = tid + i * 256;
        a_oc[i] = chunk >> 4;
        int col = chunk & 15;
        a_colx[i] = (col ^ (a_oc[i] & 15)) * 8;
    }

    u4a areg[8];
#pragma unroll
    for (int i = 0; i < 8; i++)
        areg[i] = *(const u4a*)(w2b + a_oc[i] * OCN + (tid & 15) * 8);   // s=0 slice

    f32x4 acc[8][4];
#pragma unroll
    for (int t = 0; t < 8; t++)
#pragma unroll
        for (int g = 0; g < 4; g++) acc[t][g] = (f32x4){0, 0, 0, 0};

    bf16x8 bbuf[3][4];
#pragma unroll
    for (int j0 = 0; j0 < 2; j0++) {
        int off0 = ((j0 / 4) / 3 * HP + (j0 / 4) % 3) * OCN + (j0 % 4) * 32 + q * 8;
#pragma unroll
        for (int g = 0; g < 4; g++) bbuf[j0][g] = ldb8(hb + bofs[g] + off0);
    }

#pragma unroll
    for (int i = 0; i < 8; i++)
        *(u4a*)(As + a_oc[i] * 128 + a_colx[i]) = areg[i];
    __syncthreads();

    const short* Abase = As + l16 * 128;     // + t*2048 + swizzled col
    for (int s = 0; s < 9; s++) {
        if (s < 8) {
            const short* wns = w2b + (size_t)(s + 1) * 16384;
#pragma unroll
            for (int i = 0; i < 8; i++)
                areg[i] = *(const u4a*)(wns + a_oc[i] * OCN + (tid & 15) * 8);
        }
#pragma unroll
        for (int icc = 0; icc < 4; icc++) {
            int j = s * 4 + icc;
            int jn = j + 2; if (jn > 35) jn = 35;
            int offn = ((jn >> 2) / 3 * HP + (jn >> 2) % 3) * OCN + (jn & 3) * 32 + q * 8;
#pragma unroll
            for (int g = 0; g < 4; g++) bbuf[jn % 3][g] = ldb8(hb + bofs[g] + offn);
            int colx = ((icc * 4 + q) ^ l16) * 8;
#pragma unroll
            for (int t = 0; t < 8; t++) {
                bf16x8 af = *(const bf16x8*)(Abase + t * 2048 + colx);
#pragma unroll
                for (int g = 0; g < 4; g++)
                    acc[t][g] = __builtin_amdgcn_mfma_f32_16x16x32_bf16(af, bbuf[j % 3][g], acc[t][g], 0, 0, 0);
            }
        }
        if (s < 8) {
            __syncthreads();
#pragma unroll
            for (int i = 0; i < 8; i++)
                *(u4a*)(As + a_oc[i] * 128 + a_colx[i]) = areg[i];
            __syncthreads();
        }
    }
    // C/D layout: col(px)=l16, row(oc)=q*4+reg ; store NCHW bf16
    short* on = out2b + (size_t)n * OCN * PIX2;
#pragma unroll
    for (int t = 0; t < 8; t++) {
        int ocb = t * 16 + q * 4;
#pragma unroll
        for (int g = 0; g < 4; g++) {
            if (!st[g]) continue;
            int p = pxb + g * 16;
#pragma unroll
            for (int r = 0; r < 4; r++)
                on[(size_t)(ocb + r) * PIX2 + p] = f2bf(acc[t][g][r]);
        }
    }
    // fused BN2 stats
#pragma unroll
    for (int t = 0; t < 8; t++) {
#pragma unroll
        for (int r = 0; r < 4; r++) {
            float s = 0.f, z = 0.f;
#pragma unroll
            for (int g = 0; g < 4; g++) {
                if (!st[g]) continue;
                float v = acc[t][g][r];
                s += v;
                z = fmaf(v, v, z);
            }
#pragma unroll
            for (int msk = 1; msk < 16; msk <<= 1) {
                s += __shfl_xor(s, msk, 64);
                z += __shfl_xor(z, msk, 64);
            }
            if (l16 == 0) {
                int oc = t * 16 + q * 4 + r;
                sred[wave][oc][0] = s;
                sred[wave][oc][1] = z;
            }
        }
    }
    __syncthreads();
    if (tid < OCN) {
        float s = sred[0][tid][0] + sred[1][tid][0] + sred[2][tid][0] + sred[3][tid][0];
        float z = sred[0][tid][1] + sred[1][tid][1] + sred[2][tid][1] + sred[3][tid][1];
        atomicAdd(&sum2x[n * OCN + tid], s);
        atomicAdd(&sq2x[n * OCN + tid], z);
    }
}

// BN2 affine + ReLU: NCHW bf16 temp -> fp32 d_out. 2 px per thread.
__global__ __launch_bounds__(256) void k_bnrelu(const unsigned* __restrict__ in2,
                                                float* __restrict__ y,
                                                const float* __restrict__ scale,
                                                const float* __restrict__ shift) {
    size_t i2 = (size_t)blockIdx.x * 256 + threadIdx.x;   // 25088*256 = 6,422,528 exact
    int c = (int)((i2 / (PIX2 / 2)) & (OCN - 1));
    unsigned u = in2[i2];
    float v0 = __uint_as_float(u << 16);
    float v1 = __uint_as_float(u & 0xffff0000u);
    float sc = scale[c], sh = shift[c];
    float2 o;
    o.x = fmaxf(fmaf(sc, v0, sh), 0.f);
    o.y = fmaxf(fmaf(sc, v1, sh), 0.f);
    *(float2*)(y + 2 * i2) = o;
}

// ---------------------------------------------------------------------------
extern "C" void kernel_launch(void* const* d_in, const int* in_sizes, int n_in,
                              void* d_out, int out_size, void* d_ws, size_t ws_size,
                              hipStream_t stream) {
    const float* inp = (const float*)d_in[0];
    const float* w1  = (const float*)d_in[1];
    const float* g1  = (const float*)d_in[2];
    const float* b1  = (const float*)d_in[3];
    const float* w2  = (const float*)d_in[4];
    const float* g2  = (const float*)d_in[5];
    const float* b2  = (const float*)d_in[6];
    float* out = (float*)d_out;

    char* ws = (char*)d_ws;
    int2*  map   = (int2*)ws;                         // 100,352 B
    float* stats = (float*)(ws + 102400);             // 65,536 B zeroed in k_setup
    short* w2b   = (short*)(ws + 176128);             // 294,912 B -> 471,040
    short* w1b   = (short*)(ws + 471040);             // 49,152 B  -> 520,192
    short* padA  = (short*)(ws + 520192);             // 10,736,640 B -> 11,256,832
    short* padB  = (short*)(ws + 11256832ULL);        // 10,736,640 B -> 21,993,472
    short* h2p   = (short*)(ws + 21993472ULL);        // 27,557,888 B -> 49,551,360
    short* out1b = (short*)(ws + 49551360ULL);        // 102,760,448 B -> 152,311,808
    short* out2b = (short*)(ws + 152311808ULL);       // 25,690,112 B -> 178,001,920

    float* sum1x = stats;                // 32*128
    float* sq1x  = stats + 4096;
    float* sum2x = stats + 8192;
    float* sq2x  = stats + 12288;
    float* SC1 = stats + 16384, *SH1 = stats + 16512;
    float* SC2 = stats + 16640, *SH2 = stats + 16768;

    k_setup <<<dim3(2609), 256, 0, stream>>>(w1, w1b, w2, w2b, map, stats, (unsigned*)h2p);
    k_pad   <<<dim3(PH, 96), 256, 0, stream>>>(inp, padA, padB);
    k_conv1m<<<dim3(196, BN_), 256, 0, stream>>>(padA, padB, w1b, map, out1b, sum1x, sq1x);
    k_fin2  <<<1, 128, 0, stream>>>(sum1x, sq1x, g1, b1, 1.f / (BN_ * PIX1), SC1, SH1);
    k_bnpool<<<dim3(PIX2 / 4, BN_), 256, 0, stream>>>((const unsigned*)out1b, SC1, SH1, (unsigned*)h2p);
    k_conv2m<<<dim3(416), 256, 0, stream>>>(h2p, w2b, out2b, sum2x, sq2x);
    k_fin2  <<<1, 128, 0, stream>>>(sum2x, sq2x, g2, b2, 1.f / (BN_ * PIX2), SC2, SH2);
    k_bnrelu<<<dim3(25088), 256, 0, stream>>>((const unsigned*)out2b, out, SC2, SH2);
}